// Round 3
// baseline (307.975 us; speedup 1.0000x reference)
//
#include <hip/hip_runtime.h>
#include <stdint.h>

#define NB 16
#define NC 256
#define NH 48
#define NW 160
#define HW (NH*NW)        // 7680
#define NP (NB*HW)        // 122880

static __device__ __forceinline__ unsigned short f2bf(float f){
  union { float f; uint32_t u; } v; v.f = f;
  uint32_t u = v.u;
  uint32_t r = (u + 0x7FFFu + ((u >> 16) & 1u)) >> 16;
  return (unsigned short)r;
}
static __device__ __forceinline__ float bf2f(unsigned short h){
  union { float f; uint32_t u; } v; v.u = ((uint32_t)h) << 16; return v.f;
}

// ---- KW: produce FRAGMENT-MAJOR weights so kb's A-loads are lane-contiguous.
//  WbF[(((ks*4+w)*4+mi)*64+lane)*8+j] = w_ext[m][1+k],
//      m = w*64+mi*16+(lane&15), k = ks*32+(lane>>4)*8+j
//  WtapF[((ks*64)+lane)*8+j] = (lane&15)<9 ? w_disp[k*9+(lane&15)] : 0
__global__ __launch_bounds__(256) void kw_conv(const float* __restrict__ w_ext,
                                               const float* __restrict__ w_disp,
                                               unsigned short* __restrict__ WbF,
                                               unsigned short* __restrict__ WtapF){
  int d = blockIdx.x * 256 + threadIdx.x;
  if (blockIdx.x < 256){
    int j  = d & 7;
    int lane = (d >> 3) & 63;
    int mi = (d >> 9) & 3;
    int w  = (d >> 11) & 3;
    int ks = d >> 13;
    int m = w * 64 + mi * 16 + (lane & 15);
    int k = ks * 32 + (lane >> 4) * 8 + j;
    WbF[d] = f2bf(w_ext[m * 257 + 1 + k]);
  } else {
    int d2 = d - 65536;                 // 0..4095
    int j  = d2 & 7;
    int lane = (d2 >> 3) & 63;
    int ks = d2 >> 9;
    int tap = lane & 15;
    int k = ks * 32 + (lane >> 4) * 8 + j;
    WtapF[d2] = (tap < 9) ? f2bf(w_disp[k * 9 + tap]) : (unsigned short)0;
  }
}

// ---- KB: fused transpose-stage + GEMM, SINGLE-STAGE.
//   Whole 64px x 256ch B-tile staged to 32 KB LDS (bf16, fragment-ordered,
//   [ks][unit][..]) with depth-2 register ping-pong loads, ONE barrier, then
//   8 pure-compute k-steps (ds_read_b128 + MFMA) with depth-1 A prefetch.
//   No per-step barriers; block-level overlap (3 blocks/CU) hides latency.
typedef __attribute__((ext_vector_type(8))) short bf16x8;
typedef __attribute__((ext_vector_type(4))) float f32x4;

__global__ __launch_bounds__(256, 3) void kb_gemm(
    const float* __restrict__ x,             // [NB][NC][HW] fp32
    const unsigned short* __restrict__ Wb,   // fragment-major, 65536 shorts
    const unsigned short* __restrict__ Wtap, // fragment-major, 4096 shorts
    unsigned short* __restrict__ U,          // [NB*NC][HW] bf16
    float* __restrict__ T)                   // [9][NP] fp32
{
  // [ks][unit][(n15 + kq*16)*8 + j] : 8 * 4 * 512 shorts = 32 KB
  __shared__ __align__(16) unsigned short smem[8 * 2048];
  int bx = blockIdx.x;            // 1920 = 16 b * 120 nt
  int b  = bx / 120;
  int nt = bx - b * 120;
  int p0 = nt * 64;               // hw offset within image (64 | 7680)

  int tid  = threadIdx.x;
  int lane = tid & 63;
  int w    = tid >> 6;            // wave 0..3 ; wm = w (m-quarter of 64)
  int l15 = lane & 15;
  int lq  = lane >> 4;

  // staging role: thread covers (n = tid&63, kq = tid>>6); 8 floats k-strided
  int sn  = tid & 63;
  int skq = tid >> 6;
  const float* xbase = x + ((size_t)b * NC) * HW + p0 + sn;
  unsigned short* swr = smem + (sn >> 4) * 512 + ((sn & 15) + skq * 16) * 8;

  // A fragments for ks=0 issued first (L2-hot; done long before compute)
  bf16x8 afA[4], afB[4];
  bf16x8 atA = {0,0,0,0,0,0,0,0}, atB = {0,0,0,0,0,0,0,0};
  #pragma unroll
  for (int mi = 0; mi < 4; ++mi)
    afA[mi] = *(const bf16x8*)(Wb + ((w * 4 + mi) << 9) + lane * 8);
  if (w == 0)
    atA = *(const bf16x8*)(Wtap + lane * 8);

  f32x4 zero = {0.f, 0.f, 0.f, 0.f};
  f32x4 acc[4][4];
  f32x4 acct[4];
  #pragma unroll
  for (int mi = 0; mi < 4; ++mi){
    acct[mi] = zero;
    #pragma unroll
    for (int ni = 0; ni < 4; ++ni) acc[mi][ni] = zero;
  }

  // ---- load phase: depth-2 ping-pong, no fences, one barrier at the end ----
  float rA[8], rB[8];
#define LOADX(R, KS)                                                          \
  { _Pragma("unroll")                                                         \
    for (int j = 0; j < 8; ++j)                                               \
      R[j] = xbase[(size_t)((KS) * 32 + skq * 8 + j) * HW]; }
#define CVW(R, KS)                                                            \
  { unsigned short h[8];                                                      \
    _Pragma("unroll")                                                         \
    for (int j = 0; j < 8; ++j) h[j] = f2bf(R[j]);                            \
    *(bf16x8*)(swr + (KS) * 2048) = *(bf16x8*)h; }

  LOADX(rA, 0) LOADX(rB, 1)
  CVW(rA, 0)   LOADX(rA, 2)
  CVW(rB, 1)   LOADX(rB, 3)
  CVW(rA, 2)   LOADX(rA, 4)
  CVW(rB, 3)   LOADX(rB, 5)
  CVW(rA, 4)   LOADX(rA, 6)
  CVW(rB, 5)   LOADX(rB, 7)
  CVW(rA, 6)
  CVW(rB, 7)
#undef LOADX
#undef CVW
  __syncthreads();

  // ---- compute phase: 8 steps, no barriers, depth-1 A prefetch ------------
#define KB_STEP(T_, AFC, AFN, ATC, ATN)                                       \
  {                                                                           \
    constexpr int t_ = (T_);                                                  \
    if (t_ + 1 < 8) {                                                         \
      _Pragma("unroll")                                                       \
      for (int mi = 0; mi < 4; ++mi)                                          \
        AFN[mi] = *(const bf16x8*)(Wb + (((t_ + 1) * 16 + w * 4 + mi) << 9)   \
                                   + lane * 8);                               \
      if (w == 0)                                                             \
        ATN = *(const bf16x8*)(Wtap + ((t_ + 1) << 9) + lane * 8);            \
    }                                                                         \
    bf16x8 bg[4];                                                             \
    _Pragma("unroll")                                                         \
    for (int ni = 0; ni < 4; ++ni)                                            \
      bg[ni] = *(const bf16x8*)(smem + t_ * 2048 + ni * 512 + lane * 8);      \
    _Pragma("unroll")                                                         \
    for (int mi = 0; mi < 4; ++mi)                                            \
      _Pragma("unroll")                                                       \
      for (int ni = 0; ni < 4; ++ni)                                          \
        acc[mi][ni] = __builtin_amdgcn_mfma_f32_16x16x32_bf16(AFC[mi], bg[ni],\
                                                      acc[mi][ni], 0, 0, 0);  \
    if (w == 0) {                                                             \
      _Pragma("unroll")                                                       \
      for (int ni = 0; ni < 4; ++ni)                                          \
        acct[ni] = __builtin_amdgcn_mfma_f32_16x16x32_bf16(ATC, bg[ni],       \
                                                       acct[ni], 0, 0, 0);    \
    }                                                                         \
  }

  KB_STEP(0, afA, afB, atA, atB)
  KB_STEP(1, afB, afA, atB, atA)
  KB_STEP(2, afA, afB, atA, atB)
  KB_STEP(3, afB, afA, atB, atA)
  KB_STEP(4, afA, afB, atA, atB)
  KB_STEP(5, afB, afA, atB, atA)
  KB_STEP(6, afA, afB, atA, atB)
  KB_STEP(7, afB, afA, atB, atA)
#undef KB_STEP

  // epilogue U: C/D layout col=lane&15 (n), row=lq*4+r (m)
  #pragma unroll
  for (int mi = 0; mi < 4; ++mi){
    #pragma unroll
    for (int ni = 0; ni < 4; ++ni){
      int o = w * 64 + mi * 16 + lq * 4;
      int n = ni * 16 + l15;
      size_t base = ((size_t)(b * NC + o)) * HW + p0 + n;
      #pragma unroll
      for (int r = 0; r < 4; ++r)
        U[base + (size_t)r * HW] = f2bf(acc[mi][ni][r]);
    }
  }
  // epilogue T (wave 0): row = lq*4+r = tap index, keep rows 0..8
  if (w == 0){
    #pragma unroll
    for (int ni = 0; ni < 4; ++ni){
      int n = ni * 16 + l15;
      #pragma unroll
      for (int r = 0; r < 4; ++r){
        int k = lq * 4 + r;
        if (k < 9)
          T[(size_t)k * NP + (size_t)b * HW + p0 + n] = acct[ni][r];
      }
    }
  }
}

// ---- KP: per-pixel grid params (wy, dlerp, off0, off1) ----------------------
__global__ __launch_bounds__(256) void kp_grid(
    const float* __restrict__ P2, const float* __restrict__ b_disp,
    const float* __restrict__ T, float4* __restrict__ pre)
{
  int p = blockIdx.x * 256 + threadIdx.x;   // 0..122879
  int b  = p / HW;
  int hw = p - b * HW;
  int y  = hw / NW;
  int xx = hw - y * NW;

  float d = 0.f;
  #pragma unroll
  for (int ky = 0; ky < 3; ++ky){
    int yy2 = y + ky - 1;
    if (yy2 < 0 || yy2 >= NH) continue;
    #pragma unroll
    for (int kx = 0; kx < 3; ++kx){
      int xx2 = xx + kx - 1;
      if (xx2 < 0 || xx2 >= NW) continue;
      d += T[(size_t)(ky * 3 + kx) * NP + b * HW + yy2 * NW + xx2];
    }
  }
  float th = tanhf(d + b_disp[0]);

  float fy = P2[b * 12 + 5] * 0.0625f;
  float cy = P2[b * 12 + 6] * 0.0625f;
  float Ty = P2[b * 12 + 7] * 0.0625f;

  float ysb   = fmaxf(1.535f * ((float)y - cy) / 1.765f, 0.f) * (1.f / 24.f);
  float ybase = -1.f + (float)y * (2.f / 47.f);
  float gy = ybase + ysb + 0.1f * th;
  float iy = fminf(fmaxf((gy + 1.f) * 0.5f * 47.f, 0.f), 47.f);
  float fiy0 = floorf(iy);
  float wy = iy - fiy0;
  int iy0 = (int)fiy0;
  int iy1 = min(iy0 + 1, 47);

  float inv_den = 1.f / (fabsf(fy * 1.65f + Ty) + 1e-10f);
  float dr0 = fmaxf(fy * 0.54f * ((float)iy0 - cy) * inv_den, 0.f);
  float dr1 = fmaxf(fy * 0.54f * ((float)iy1 - cy) * inv_den, 0.f);
  float dlerp = (1.f - wy) * dr0 + wy * dr1;

  float4 pr;
  pr.x = wy; pr.y = dlerp;
  pr.z = __int_as_float(iy0 * NW + xx);
  pr.w = __int_as_float(iy1 * NW + xx);
  pre[p] = pr;
}

// ---- KC: lerp + matvec-residual ReLU, split over 8 channel groups ----------
__global__ __launch_bounds__(256) void kc_epilogue(
    const float* __restrict__ x, const float* __restrict__ w_ext,
    const float* __restrict__ b_ext, const float* __restrict__ alpha,
    const unsigned short* __restrict__ U, const float4* __restrict__ pre,
    float* __restrict__ out)
{
  int bx = blockIdx.x;            // 3840 = 480 ptile * 8 cg
  int ptile = bx >> 3;
  int cg    = bx & 7;
  int p = ptile * 256 + threadIdx.x;
  int b  = p / HW;
  int hw = p - b * HW;

  float4 pr = pre[p];
  float wy    = pr.x;
  float dlerp = pr.y;
  int off0 = __float_as_int(pr.z);
  int off1 = __float_as_int(pr.w);
  float w1 = 1.f - wy;
  float al = alpha[0];

  size_t base0 = (size_t)(b * NC) * HW;
  const unsigned short* Ub = U + base0;
  const float* xb = x + base0 + hw;
  float* ob = out + base0 + hw;

  int o0 = cg * 32;
  #pragma unroll 4
  for (int o = o0; o < o0 + 32; ++o){
    float u0 = bf2f(Ub[(size_t)o * HW + off0]);
    float u1 = bf2f(Ub[(size_t)o * HW + off1]);
    float val = w1 * u0 + wy * u1 + w_ext[o * 257] * dlerp + b_ext[o];
    float r = xb[(size_t)o * HW] + al * val;
    ob[(size_t)o * HW] = fmaxf(r, 0.f);
  }
}

// ---------------------------------------------------------------------------
extern "C" void kernel_launch(void* const* d_in, const int* in_sizes, int n_in,
                              void* d_out, int out_size, void* d_ws, size_t ws_size,
                              hipStream_t stream) {
  const float* features = (const float*)d_in[0];
  const float* P2       = (const float*)d_in[1];
  const float* w_disp   = (const float*)d_in[2];
  const float* b_disp   = (const float*)d_in[3];
  const float* w_ext    = (const float*)d_in[4];
  const float* b_ext    = (const float*)d_in[5];
  const float* alpha    = (const float*)d_in[6];
  float* out = (float*)d_out;

  char* ws = (char*)d_ws;
  const size_t U_bytes   = (size_t)NP * 256 * 2;    // 62,914,560
  const size_t T_bytes   = (size_t)9 * NP * 4;      //  4,423,680
  const size_t pre_bytes = (size_t)NP * 16;         //  1,966,080
  unsigned short* U    = (unsigned short*)ws;
  float*          T    = (float*)(ws + U_bytes);
  float4*         pre  = (float4*)(ws + U_bytes + T_bytes);
  unsigned short* Wb   = (unsigned short*)(ws + U_bytes + T_bytes + pre_bytes);
  unsigned short* Wtap = Wb + 256 * 256;

  hipLaunchKernelGGL(kw_conv,     dim3(272),  dim3(256), 0, stream, w_ext, w_disp, Wb, Wtap);
  hipLaunchKernelGGL(kb_gemm,     dim3(1920), dim3(256), 0, stream, features, Wb, Wtap, U, T);
  hipLaunchKernelGGL(kp_grid,     dim3(480),  dim3(256), 0, stream, P2, b_disp, T, pre);
  hipLaunchKernelGGL(kc_epilogue, dim3(3840), dim3(256), 0, stream,
                     features, w_ext, b_ext, alpha, U, pre, out);
}

// Round 4
// 303.933 us; speedup vs baseline: 1.0133x; 1.0133x over previous
//
#include <hip/hip_runtime.h>
#include <stdint.h>

#define NB 16
#define NC 256
#define NH 48
#define NW 160
#define HW (NH*NW)        // 7680
#define NP (NB*HW)        // 122880

static __device__ __forceinline__ unsigned short f2bf(float f){
  union { float f; uint32_t u; } v; v.f = f;
  uint32_t u = v.u;
  uint32_t r = (u + 0x7FFFu + ((u >> 16) & 1u)) >> 16;
  return (unsigned short)r;
}
static __device__ __forceinline__ float bf2f(unsigned short h){
  union { float f; uint32_t u; } v; v.u = ((uint32_t)h) << 16; return v.f;
}

// ---- KW: produce FRAGMENT-MAJOR weights so kb's A-loads are lane-contiguous.
__global__ __launch_bounds__(256) void kw_conv(const float* __restrict__ w_ext,
                                               const float* __restrict__ w_disp,
                                               unsigned short* __restrict__ WbF,
                                               unsigned short* __restrict__ WtapF){
  int d = blockIdx.x * 256 + threadIdx.x;
  if (blockIdx.x < 256){
    int j  = d & 7;
    int lane = (d >> 3) & 63;
    int mi = (d >> 9) & 3;
    int w  = (d >> 11) & 3;
    int ks = d >> 13;
    int m = w * 64 + mi * 16 + (lane & 15);
    int k = ks * 32 + (lane >> 4) * 8 + j;
    WbF[d] = f2bf(w_ext[m * 257 + 1 + k]);
  } else {
    int d2 = d - 65536;                 // 0..4095
    int j  = d2 & 7;
    int lane = (d2 >> 3) & 63;
    int ks = d2 >> 9;
    int tap = lane & 15;
    int k = ks * 32 + (lane >> 4) * 8 + j;
    WtapF[d2] = (tap < 9) ? f2bf(w_disp[k * 9 + tap]) : (unsigned short)0;
  }
}

// ---- KB: fused transpose-stage + GEMM, SINGLE-STAGE, dwordx2 staging.
//   Staging: thread = (pixel-pair q, 32-ch group cg). 32 global_load_dwordx2
//   ALL issued up-front (depth-32, 512 B per wave-instr), then 4 group-wise
//   convert + 2x ds_write_b128 passes (vmcnt steps down 24/16/8/0).
//   One barrier, then 8 pure-compute k-steps with depth-1 A prefetch.
typedef __attribute__((ext_vector_type(8))) short bf16x8;
typedef __attribute__((ext_vector_type(4))) float f32x4;

__global__ __launch_bounds__(256, 2) void kb_gemm(
    const float* __restrict__ x,             // [NB][NC][HW] fp32
    const unsigned short* __restrict__ Wb,   // fragment-major, 65536 shorts
    const unsigned short* __restrict__ Wtap, // fragment-major, 4096 shorts
    unsigned short* __restrict__ U,          // [NB*NC][HW] bf16
    float* __restrict__ T)                   // [9][NP] fp32
{
  // [ks][unit][(n15 + kq*16)*8 + j] : 8 * 4 * 512 shorts = 32 KB
  __shared__ __align__(16) unsigned short smem[8 * 2048];
  int bx = blockIdx.x;            // 1920 = 16 b * 120 nt
  int b  = bx / 120;
  int nt = bx - b * 120;
  int p0 = nt * 64;               // hw offset within image (64 | 7680)

  int tid  = threadIdx.x;
  int lane = tid & 63;
  int w    = tid >> 6;            // wave 0..3 ; wm = w (m-quarter of 64)
  int l15 = lane & 15;
  int lq  = lane >> 4;

  // ---- staging loads: issue ALL 32 dwordx2 before anything else ----------
  int q  = tid & 31;              // pixel pair: n = 2q, 2q+1
  int cg = tid >> 5;              // 0..7 : channels cg*32 .. cg*32+31 (= k-step)
  const float* xs = x + ((size_t)b * NC + (size_t)cg * 32) * HW + p0 + 2 * q;

  float2 v[32];
  #pragma unroll
  for (int i = 0; i < 32; ++i)
    v[i] = *(const float2*)(xs + (size_t)i * HW);

  // A fragments for ks=0 (L2-hot) issued after the x loads
  bf16x8 afA[4], afB[4];
  bf16x8 atA = {0,0,0,0,0,0,0,0}, atB = {0,0,0,0,0,0,0,0};
  #pragma unroll
  for (int mi = 0; mi < 4; ++mi)
    afA[mi] = *(const bf16x8*)(Wb + ((w * 4 + mi) << 9) + lane * 8);
  if (w == 0)
    atA = *(const bf16x8*)(Wtap + lane * 8);

  f32x4 zero = {0.f, 0.f, 0.f, 0.f};
  f32x4 acc[4][4];
  f32x4 acct[4];
  #pragma unroll
  for (int mi = 0; mi < 4; ++mi){
    acct[mi] = zero;
    #pragma unroll
    for (int ni = 0; ni < 4; ++ni) acc[mi][ni] = zero;
  }

  // ---- convert + LDS write, group-wise as loads arrive --------------------
  {
    int n0 = 2 * q;                         // even, n0 and n0+1 share a unit
    unsigned short* sw0 = smem + cg * 2048 + (n0 >> 4) * 512;
    int n15a = n0 & 15;
    #pragma unroll
    for (int g = 0; g < 4; ++g){
      unsigned short ha[8], hb[8];
      #pragma unroll
      for (int j = 0; j < 8; ++j){
        ha[j] = f2bf(v[8 * g + j].x);
        hb[j] = f2bf(v[8 * g + j].y);
      }
      *(bf16x8*)(sw0 + (n15a     + g * 16) * 8) = *(bf16x8*)ha;
      *(bf16x8*)(sw0 + (n15a + 1 + g * 16) * 8) = *(bf16x8*)hb;
    }
  }
  __syncthreads();

  // ---- compute phase: 8 steps, no barriers, depth-1 A prefetch ------------
#define KB_STEP(T_, AFC, AFN, ATC, ATN)                                       \
  {                                                                           \
    constexpr int t_ = (T_);                                                  \
    if (t_ + 1 < 8) {                                                         \
      _Pragma("unroll")                                                       \
      for (int mi = 0; mi < 4; ++mi)                                          \
        AFN[mi] = *(const bf16x8*)(Wb + (((t_ + 1) * 16 + w * 4 + mi) << 9)   \
                                   + lane * 8);                               \
      if (w == 0)                                                             \
        ATN = *(const bf16x8*)(Wtap + ((t_ + 1) << 9) + lane * 8);            \
    }                                                                         \
    bf16x8 bg[4];                                                             \
    _Pragma("unroll")                                                         \
    for (int ni = 0; ni < 4; ++ni)                                            \
      bg[ni] = *(const bf16x8*)(smem + t_ * 2048 + ni * 512 + lane * 8);      \
    _Pragma("unroll")                                                         \
    for (int mi = 0; mi < 4; ++mi)                                            \
      _Pragma("unroll")                                                       \
      for (int ni = 0; ni < 4; ++ni)                                          \
        acc[mi][ni] = __builtin_amdgcn_mfma_f32_16x16x32_bf16(AFC[mi], bg[ni],\
                                                      acc[mi][ni], 0, 0, 0);  \
    if (w == 0) {                                                             \
      _Pragma("unroll")                                                       \
      for (int ni = 0; ni < 4; ++ni)                                          \
        acct[ni] = __builtin_amdgcn_mfma_f32_16x16x32_bf16(ATC, bg[ni],       \
                                                       acct[ni], 0, 0, 0);    \
    }                                                                         \
  }

  KB_STEP(0, afA, afB, atA, atB)
  KB_STEP(1, afB, afA, atB, atA)
  KB_STEP(2, afA, afB, atA, atB)
  KB_STEP(3, afB, afA, atB, atA)
  KB_STEP(4, afA, afB, atA, atB)
  KB_STEP(5, afB, afA, atB, atA)
  KB_STEP(6, afA, afB, atA, atB)
  KB_STEP(7, afB, afA, atB, atA)
#undef KB_STEP

  // epilogue U: C/D layout col=lane&15 (n), row=lq*4+r (m)
  #pragma unroll
  for (int mi = 0; mi < 4; ++mi){
    #pragma unroll
    for (int ni = 0; ni < 4; ++ni){
      int o = w * 64 + mi * 16 + lq * 4;
      int n = ni * 16 + l15;
      size_t base = ((size_t)(b * NC + o)) * HW + p0 + n;
      #pragma unroll
      for (int r = 0; r < 4; ++r)
        U[base + (size_t)r * HW] = f2bf(acc[mi][ni][r]);
    }
  }
  // epilogue T (wave 0): row = lq*4+r = tap index, keep rows 0..8
  if (w == 0){
    #pragma unroll
    for (int ni = 0; ni < 4; ++ni){
      int n = ni * 16 + l15;
      #pragma unroll
      for (int r = 0; r < 4; ++r){
        int k = lq * 4 + r;
        if (k < 9)
          T[(size_t)k * NP + (size_t)b * HW + p0 + n] = acct[ni][r];
      }
    }
  }
}

// ---- KP: per-pixel grid params (wy, dlerp, off0, off1) ----------------------
__global__ __launch_bounds__(256) void kp_grid(
    const float* __restrict__ P2, const float* __restrict__ b_disp,
    const float* __restrict__ T, float4* __restrict__ pre)
{
  int p = blockIdx.x * 256 + threadIdx.x;   // 0..122879
  int b  = p / HW;
  int hw = p - b * HW;
  int y  = hw / NW;
  int xx = hw - y * NW;

  float d = 0.f;
  #pragma unroll
  for (int ky = 0; ky < 3; ++ky){
    int yy2 = y + ky - 1;
    if (yy2 < 0 || yy2 >= NH) continue;
    #pragma unroll
    for (int kx = 0; kx < 3; ++kx){
      int xx2 = xx + kx - 1;
      if (xx2 < 0 || xx2 >= NW) continue;
      d += T[(size_t)(ky * 3 + kx) * NP + b * HW + yy2 * NW + xx2];
    }
  }
  float th = tanhf(d + b_disp[0]);

  float fy = P2[b * 12 + 5] * 0.0625f;
  float cy = P2[b * 12 + 6] * 0.0625f;
  float Ty = P2[b * 12 + 7] * 0.0625f;

  float ysb   = fmaxf(1.535f * ((float)y - cy) / 1.765f, 0.f) * (1.f / 24.f);
  float ybase = -1.f + (float)y * (2.f / 47.f);
  float gy = ybase + ysb + 0.1f * th;
  float iy = fminf(fmaxf((gy + 1.f) * 0.5f * 47.f, 0.f), 47.f);
  float fiy0 = floorf(iy);
  float wy = iy - fiy0;
  int iy0 = (int)fiy0;
  int iy1 = min(iy0 + 1, 47);

  float inv_den = 1.f / (fabsf(fy * 1.65f + Ty) + 1e-10f);
  float dr0 = fmaxf(fy * 0.54f * ((float)iy0 - cy) * inv_den, 0.f);
  float dr1 = fmaxf(fy * 0.54f * ((float)iy1 - cy) * inv_den, 0.f);
  float dlerp = (1.f - wy) * dr0 + wy * dr1;

  float4 pr;
  pr.x = wy; pr.y = dlerp;
  pr.z = __int_as_float(iy0 * NW + xx);
  pr.w = __int_as_float(iy1 * NW + xx);
  pre[p] = pr;
}

// ---- KC: lerp + matvec-residual ReLU, split over 8 channel groups ----------
__global__ __launch_bounds__(256) void kc_epilogue(
    const float* __restrict__ x, const float* __restrict__ w_ext,
    const float* __restrict__ b_ext, const float* __restrict__ alpha,
    const unsigned short* __restrict__ U, const float4* __restrict__ pre,
    float* __restrict__ out)
{
  int bx = blockIdx.x;            // 3840 = 480 ptile * 8 cg
  int ptile = bx >> 3;
  int cg    = bx & 7;
  int p = ptile * 256 + threadIdx.x;
  int b  = p / HW;
  int hw = p - b * HW;

  float4 pr = pre[p];
  float wy    = pr.x;
  float dlerp = pr.y;
  int off0 = __float_as_int(pr.z);
  int off1 = __float_as_int(pr.w);
  float w1 = 1.f - wy;
  float al = alpha[0];

  size_t base0 = (size_t)(b * NC) * HW;
  const unsigned short* Ub = U + base0;
  const float* xb = x + base0 + hw;
  float* ob = out + base0 + hw;

  int o0 = cg * 32;
  #pragma unroll 4
  for (int o = o0; o < o0 + 32; ++o){
    float u0 = bf2f(Ub[(size_t)o * HW + off0]);
    float u1 = bf2f(Ub[(size_t)o * HW + off1]);
    float val = w1 * u0 + wy * u1 + w_ext[o * 257] * dlerp + b_ext[o];
    float r = xb[(size_t)o * HW] + al * val;
    ob[(size_t)o * HW] = fmaxf(r, 0.f);
  }
}

// ---------------------------------------------------------------------------
extern "C" void kernel_launch(void* const* d_in, const int* in_sizes, int n_in,
                              void* d_out, int out_size, void* d_ws, size_t ws_size,
                              hipStream_t stream) {
  const float* features = (const float*)d_in[0];
  const float* P2       = (const float*)d_in[1];
  const float* w_disp   = (const float*)d_in[2];
  const float* b_disp   = (const float*)d_in[3];
  const float* w_ext    = (const float*)d_in[4];
  const float* b_ext    = (const float*)d_in[5];
  const float* alpha    = (const float*)d_in[6];
  float* out = (float*)d_out;

  char* ws = (char*)d_ws;
  const size_t U_bytes   = (size_t)NP * 256 * 2;    // 62,914,560
  const size_t T_bytes   = (size_t)9 * NP * 4;      //  4,423,680
  const size_t pre_bytes = (size_t)NP * 16;         //  1,966,080
  unsigned short* U    = (unsigned short*)ws;
  float*          T    = (float*)(ws + U_bytes);
  float4*         pre  = (float4*)(ws + U_bytes + T_bytes);
  unsigned short* Wb   = (unsigned short*)(ws + U_bytes + T_bytes + pre_bytes);
  unsigned short* Wtap = Wb + 256 * 256;

  hipLaunchKernelGGL(kw_conv,     dim3(272),  dim3(256), 0, stream, w_ext, w_disp, Wb, Wtap);
  hipLaunchKernelGGL(kb_gemm,     dim3(1920), dim3(256), 0, stream, features, Wb, Wtap, U, T);
  hipLaunchKernelGGL(kp_grid,     dim3(480),  dim3(256), 0, stream, P2, b_disp, T, pre);
  hipLaunchKernelGGL(kc_epilogue, dim3(3840), dim3(256), 0, stream,
                     features, w_ext, b_ext, alpha, U, pre, out);
}